// Round 7
// baseline (796.249 us; speedup 1.0000x reference)
//
#include <hip/hip_runtime.h>
#include <hip/hip_bf16.h>
#include <math.h>

// B=4096, S=200, D=64, H=36
#define BB 4096
#define SS 200
#define DD 64
#define HH 36
#define NP 48            // H padded to 3 n-tiles of 16
#define LDH 72           // bf16 LDS row stride: 144 B rows -> 16B-aligned b128
#define NROWSF (4096.0f * 200.0f)
#define NPB (2 * BB)     // 8192 segments: (b, half)
#define PSTRIDE 80       // partial-stat row stride (dwords)
#define HSLOT 768        // bf16 per (segment, tile) h slot = 16 rows x 48 cols
#define GRID 1024        // fused grid: 4 blocks/CU, capacity 5/CU (no deadlock)
#define BPB 4            // b's per fused block (1024*4 = 4096)

typedef short bf16x8 __attribute__((ext_vector_type(8)));
typedef float f32x4 __attribute__((ext_vector_type(4)));

__device__ __forceinline__ unsigned short f2bf(float f) {
    union { float f; unsigned u; } v; v.f = f;
    unsigned r = v.u + 0x7FFFu + ((v.u >> 16) & 1u);   // RNE
    return (unsigned short)(r >> 16);
}
__device__ __forceinline__ unsigned f2bf2(float a, float b) {
    union { __hip_bfloat162 h; unsigned u; } v;
    v.h = __float22bfloat162_rn(float2{a, b});         // a->low, b->high
    return v.u;
}
__device__ __forceinline__ float bf2f(unsigned short h) {
    union { unsigned u; float f; } v; v.u = (unsigned)h << 16;
    return v.f;
}
__device__ __forceinline__ float2 bf2x2(unsigned u) {
    union { unsigned q; float f; } a, b;
    a.q = u << 16; b.q = u & 0xFFFF0000u;
    return float2{a.f, b.f};
}

__device__ __forceinline__ void load_bfrags(const unsigned short* shWbT, int lane,
                                            bf16x8 (&bfr)[3][2]) {
    int col = lane & 15, q = lane >> 4;
#pragma unroll
    for (int nt = 0; nt < 3; ++nt)
#pragma unroll
        for (int kt = 0; kt < 2; ++kt)
            bfr[nt][kt] = *(const bf16x8*)&shWbT[(nt * 16 + col) * LDH + kt * 32 + q * 8];
}

__device__ __forceinline__ void gemm_tile(const unsigned short* shH,
                                          const bf16x8 (&bfr)[3][2], int mt, int lane,
                                          f32x4 (&d)[3]) {
    int m = mt * 16 + (lane & 15), q = lane >> 4;
    d[0] = f32x4{0.f, 0.f, 0.f, 0.f};
    d[1] = f32x4{0.f, 0.f, 0.f, 0.f};
    d[2] = f32x4{0.f, 0.f, 0.f, 0.f};
#pragma unroll
    for (int kt = 0; kt < 2; ++kt) {
        bf16x8 a = *(const bf16x8*)&shH[m * LDH + kt * 32 + q * 8];
#pragma unroll
        for (int nt = 0; nt < 3; ++nt)
            d[nt] = __builtin_amdgcn_mfma_f32_16x16x32_bf16(a, bfr[nt][kt], d[nt], 0, 0, 0);
    }
}

// Device-scope grid barrier. Safe: counters monotone (replays can't hang),
// grid (1024) < guaranteed resident capacity (5 blocks/CU * 256 CU = 1280).
__device__ __forceinline__ void gridbar(unsigned* ctr, unsigned goal) {
    __syncthreads();
    if (threadIdx.x == 0) {
        __hip_atomic_fetch_add(ctr, 1u, __ATOMIC_RELEASE, __HIP_MEMORY_SCOPE_AGENT);
        while (__hip_atomic_load(ctr, __ATOMIC_ACQUIRE, __HIP_MEMORY_SCOPE_AGENT) < goal)
            __builtin_amdgcn_s_sleep(8);
    }
    __syncthreads();
}

// ---------------------------------------------------------------------------
// Fused persistent kernel: phase A (fold + GEMM + stats + h-store), grid
// barrier, stats reduce, grid barrier, phase B (restage fp32 + h-reload +
// Dice epilogue + LDS pooling + direct out write).
// LDS: 28672 (union: bf16 H 16128 + WbT 6912 | fp32 H 28672) + 2752 misc.
// ---------------------------------------------------------------------------
__global__ __launch_bounds__(256, 5) void k_fused(
    const float* __restrict__ hist, const float* __restrict__ cand,
    const float* __restrict__ W1, const float* __restrict__ b1,
    const float* __restrict__ gamma, const float* __restrict__ beta,
    const float* __restrict__ alpha, const float* __restrict__ W2,
    const float* __restrict__ b2, float* __restrict__ out,
    unsigned short* __restrict__ hG, float* __restrict__ pstat,
    float* __restrict__ Af, float* __restrict__ Bcf, unsigned* __restrict__ ctr) {
    __shared__ __align__(16) char shBuf[112 * 64 * 4];     // 28672
    __shared__ __align__(16) char shMisc[2752];
    unsigned short* shH = (unsigned short*)shBuf;           // A: 112x72 bf16
    unsigned short* shWbT = (unsigned short*)(shBuf + 16128);  // A: 48x72 bf16
    float* shF = (float*)shBuf;                             // B: 112x64 fp32
    float* shC = (float*)shMisc;                            // A: 64
    float* shBase = (float*)(shMisc + 256);                 // A: 48
    float(*shBaseP)[NP] = (float(*)[NP])(shMisc + 448);     // A: 4x48
    float(*shP1)[NP] = (float(*)[NP])(shMisc + 1216);       // A: 4x48
    float(*shP2)[NP] = (float(*)[NP])(shMisc + 1984);       // A: 4x48
    float* shW = (float*)shMisc;                            // B: 112
    float(*shPool)[DD] = (float(*)[DD])(shMisc + 448);      // B: 4x64

    const int blk = blockIdx.x, t = threadIdx.x, wave = t >> 6, lane = t & 63;
    const int col = lane & 15, q = lane >> 4;

    // ======================= PHASE A =======================
    float cs1[3] = {0.f, 0.f, 0.f}, cs2[3] = {0.f, 0.f, 0.f};
    for (int bi = 0; bi < BPB; ++bi) {
        const int b = blk + bi * GRID;
        __syncthreads();                       // shC/shWbT/shH reuse guard
        if (t < DD) shC[t] = cand[b * DD + t];
        __syncthreads();
        // fold Wb -> shWbT (bf16, transposed), base partials
        for (int e = t; e < NP * DD; e += 256) {
            int n = e >> 6, k = e & 63;
            float val = 0.f;
            if (n < HH)
                val = W1[(DD + k) * HH + n] - W1[(2 * DD + k) * HH + n] +
                      shC[k] * W1[(3 * DD + k) * HH + n];
            shWbT[n * LDH + k] = f2bf(val);
        }
        if (t < 4 * NP) {
            int g = t / NP, j = t - g * NP;
            float p = 0.f;
            if (j < HH) {
#pragma unroll 4
                for (int k = 16 * g; k < 16 * g + 16; ++k)
                    p += shC[k] * (W1[k * HH + j] + W1[(2 * DD + k) * HH + j]);
            }
            shBaseP[g][j] = p;
        }
        __syncthreads();
        if (t < NP) {
            float val = (t < HH) ? b1[t] : 0.f;
            shBase[t] = val + shBaseP[0][t] + shBaseP[1][t] + shBaseP[2][t] +
                        shBaseP[3][t];
        }
        __syncthreads();
        bf16x8 bfr[3][2];
        load_bfrags(shWbT, lane, bfr);         // once per b (persists both halves)
        float basev[3];
#pragma unroll
        for (int nt = 0; nt < 3; ++nt) basev[nt] = shBase[nt * 16 + col];

        for (int half = 0; half < 2; ++half) {
            if (half) __syncthreads();          // shH reuse guard
            // stage half of hist: fp32 -> bf16 LDS
            const float4* src =
                (const float4*)(hist + ((size_t)b * SS + (half ? 112 : 0)) * DD);
            float4 v[7];
            if (!half) {
#pragma unroll
                for (int u = 0; u < 7; ++u) v[u] = src[t + u * 256];
            } else {
#pragma unroll
                for (int u = 0; u < 5; ++u) v[u] = src[t + u * 256];
                if (t < 128) v[5] = src[t + 1280];
                *(unsigned*)&shH[(88 + (t >> 5)) * LDH + (t & 31) * 2] = 0;  // pads
            }
#pragma unroll
            for (int u = 0; u < 7; ++u) {
                int i = t + u * 256;
                bool act = half ? (u < 5 || (u == 5 && t < 128)) : true;
                if (u < 6 || !half) {
                    if (act) {
                        int s = i >> 4, c = i & 15;
                        uint2 o = {f2bf2(v[u].x, v[u].y), f2bf2(v[u].z, v[u].w)};
                        *(uint2*)&shH[s * LDH + c * 4] = o;
                    }
                }
            }
            __syncthreads();
            const int seg = (b << 1) | half;
            const int NTl = half ? 6 : 7;
            for (int mt = wave; mt < NTl; mt += 4) {
                f32x4 d[3];
                gemm_tile(shH, bfr, mt, lane, d);
                float vv[3][4];
#pragma unroll
                for (int nt = 0; nt < 3; ++nt)
#pragma unroll
                    for (int r = 0; r < 4; ++r) vv[nt][r] = d[nt][r] + basev[nt];
                uint2* hp2 = (uint2*)(hG + ((size_t)seg * 7 + mt) * HSLOT);
#pragma unroll
                for (int nt = 0; nt < 3; ++nt) {
                    uint2 o = {f2bf2(vv[nt][0], vv[nt][1]), f2bf2(vv[nt][2], vv[nt][3])};
                    hp2[nt * 64 + lane] = o;
                }
                if (half && mt == 5) {          // ragged tile: exclude pad rows
                    int grow0 = 192 + q * 4;
#pragma unroll
                    for (int nt = 0; nt < 3; ++nt)
#pragma unroll
                        for (int r = 0; r < 4; ++r)
                            if (grow0 + r < SS) {
                                cs1[nt] += vv[nt][r];
                                cs2[nt] += vv[nt][r] * vv[nt][r];
                            }
                } else {
#pragma unroll
                    for (int nt = 0; nt < 3; ++nt)
#pragma unroll
                        for (int r = 0; r < 4; ++r) {
                            cs1[nt] += vv[nt][r];
                            cs2[nt] += vv[nt][r] * vv[nt][r];
                        }
                }
            }
        }
    }
    // block-level stats partial -> pstat[blk]
#pragma unroll
    for (int nt = 0; nt < 3; ++nt) {
        cs1[nt] += __shfl_xor(cs1[nt], 16);
        cs1[nt] += __shfl_xor(cs1[nt], 32);
        cs2[nt] += __shfl_xor(cs2[nt], 16);
        cs2[nt] += __shfl_xor(cs2[nt], 32);
    }
    __syncthreads();                            // shP1/shP2 alias guard
    if (lane < 16) {
#pragma unroll
        for (int nt = 0; nt < 3; ++nt) {
            shP1[wave][nt * 16 + lane] = cs1[nt];
            shP2[wave][nt * 16 + lane] = cs2[nt];
        }
    }
    __syncthreads();
    if (t < HH)
        pstat[(size_t)blk * PSTRIDE + t] =
            shP1[0][t] + shP1[1][t] + shP1[2][t] + shP1[3][t];
    else if (t < 2 * HH) {
        int f = t - HH;
        pstat[(size_t)blk * PSTRIDE + t] =
            shP2[0][f] + shP2[1][f] + shP2[2][f] + shP2[3][f];
    }

    gridbar(ctr + 0, GRID);

    // ================= STATS REDUCE (blocks 0..47) =================
    if (blk < NP) {
        if (blk < HH) {
            float s1 = 0.f, s2 = 0.f;
#pragma unroll
            for (int rr = 0; rr < GRID / 256; ++rr) {
                int r = t + rr * 256;
                s1 += pstat[(size_t)r * PSTRIDE + blk];
                s2 += pstat[(size_t)r * PSTRIDE + HH + blk];
            }
#pragma unroll
            for (int off = 1; off < 64; off <<= 1) {
                s1 += __shfl_xor(s1, off);
                s2 += __shfl_xor(s2, off);
            }
            __syncthreads();                    // reuse shP1 row 0 as scratch
            if (lane == 0) { shP1[0][wave] = s1; shP1[0][4 + wave] = s2; }
            __syncthreads();
            if (t == 0) {
                s1 = shP1[0][0] + shP1[0][1] + shP1[0][2] + shP1[0][3];
                s2 = shP1[0][4] + shP1[0][5] + shP1[0][6] + shP1[0][7];
                float mu = s1 * (1.0f / NROWSF);
                float var = s2 * (1.0f / NROWSF) - mu * mu;
                float a = rsqrtf(var + 1e-5f) * gamma[blk];
                Af[blk] = a;
                Bcf[blk] = beta[blk] - mu * a;
            }
        } else if (t == 0) {
            Af[blk] = 0.f;
            Bcf[blk] = 0.f;
        }
    }

    gridbar(ctr + 1, GRID);

    // ======================= PHASE B =======================
    float Ar[3], Br[3], W2r[3];
#pragma unroll
    for (int nt = 0; nt < 3; ++nt) {
        int c = nt * 16 + col;
        Ar[nt] = Af[c];
        Br[nt] = Bcf[c];
        W2r[nt] = (c < HH) ? W2[c] : 0.f;
    }
    const float alv = alpha[0], one_m_alv = 1.0f - alv, b2v = b2[0];

    for (int bi = 0; bi < BPB; ++bi) {
        const int b = blk + bi * GRID;
        float pacc = 0.f;
        for (int half = 0; half < 2; ++half) {
            __syncthreads();                    // shF/shW reuse guard
            // restage half of hist as fp32 (L3-hot, deep float4 loads)
            const float4* src =
                (const float4*)(hist + ((size_t)b * SS + (half ? 112 : 0)) * DD);
            float4* dstF = (float4*)shF;
            float4 v[7];
            if (!half) {
#pragma unroll
                for (int u = 0; u < 7; ++u) v[u] = src[t + u * 256];
#pragma unroll
                for (int u = 0; u < 7; ++u) dstF[t + u * 256] = v[u];
            } else {
#pragma unroll
                for (int u = 0; u < 5; ++u) v[u] = src[t + u * 256];
                if (t < 128) v[5] = src[t + 1280];
#pragma unroll
                for (int u = 0; u < 5; ++u) dstF[t + u * 256] = v[u];
                if (t < 128) dstF[t + 1280] = v[5];
            }
            const int seg = (b << 1) | half;
            const int NTl = half ? 6 : 7;
            for (int mt = wave; mt < NTl; mt += 4) {
                const uint2* hp2 =
                    (const uint2*)(hG + ((size_t)seg * 7 + mt) * HSLOT);
                uint2 hr[3];
#pragma unroll
                for (int nt = 0; nt < 3; ++nt) hr[nt] = hp2[nt * 64 + lane];
                float h[3][4];
#pragma unroll
                for (int nt = 0; nt < 3; ++nt) {
                    float2 lo = bf2x2(hr[nt].x), hi = bf2x2(hr[nt].y);
                    h[nt][0] = fmaf(lo.x, Ar[nt], Br[nt]);
                    h[nt][1] = fmaf(lo.y, Ar[nt], Br[nt]);
                    h[nt][2] = fmaf(hi.x, Ar[nt], Br[nt]);
                    h[nt][3] = fmaf(hi.y, Ar[nt], Br[nt]);
                }
                float s1[4], s2[4], wsum[4];
#pragma unroll
                for (int r = 0; r < 4; ++r) {
                    s1[r] = h[0][r] + h[1][r] + h[2][r];
                    s2[r] = h[0][r] * h[0][r] + h[1][r] * h[1][r] + h[2][r] * h[2][r];
                    s1[r] += __shfl_xor(s1[r], 1);
                    s1[r] += __shfl_xor(s1[r], 2);
                    s1[r] += __shfl_xor(s1[r], 4);
                    s1[r] += __shfl_xor(s1[r], 8);
                    s2[r] += __shfl_xor(s2[r], 1);
                    s2[r] += __shfl_xor(s2[r], 2);
                    s2[r] += __shfl_xor(s2[r], 4);
                    s2[r] += __shfl_xor(s2[r], 8);
                }
#pragma unroll
                for (int r = 0; r < 4; ++r) {
                    float avg = s1[r] * (1.0f / (float)HH);
                    float var = s2[r] * (1.0f / (float)HH) - avg * avg;
                    float inv = rsqrtf(var + 1e-3f);
                    float wv = 0.f;
#pragma unroll
                    for (int nt = 0; nt < 3; ++nt) {
                        float z = (h[nt][r] - avg) * inv;
                        float ps = 1.0f / (1.0f + __expf(-z));
                        float f = fmaf(ps, one_m_alv, alv);
                        wv = fmaf(h[nt][r] * f, W2r[nt], wv);
                    }
                    wsum[r] = wv;
                    wsum[r] += __shfl_xor(wsum[r], 1);
                    wsum[r] += __shfl_xor(wsum[r], 2);
                    wsum[r] += __shfl_xor(wsum[r], 4);
                    wsum[r] += __shfl_xor(wsum[r], 8);
                }
                if (col == 0) {                 // pad rows -> shW[88..95], unread
                    float4 o = {wsum[0] + b2v, wsum[1] + b2v, wsum[2] + b2v,
                                wsum[3] + b2v};
                    *(float4*)&shW[mt * 16 + q * 4] = o;
                }
            }
            __syncthreads();                    // shW + shF complete
            const int nR = half ? 88 : 112;
            for (int s = wave; s < nR; s += 4)
                pacc = fmaf(shW[s], shF[s * DD + lane], pacc);
        }
        __syncthreads();                        // shPool alias guard
        shPool[wave][lane] = pacc;
        __syncthreads();
        if (t < DD)                             // sole owner of b: plain store
            out[b * DD + t] =
                shPool[0][t] + shPool[1][t] + shPool[2][t] + shPool[3][t];
    }
}

// ===========================================================================
// Fallback kernels (R5 structure) for small workspaces
// ===========================================================================
__global__ __launch_bounds__(256) void k_wb(const float* __restrict__ cand,
                                            const float* __restrict__ W1,
                                            const float* __restrict__ b1,
                                            unsigned short* __restrict__ WbG,
                                            float* __restrict__ baseG) {
    int b = blockIdx.x, t = threadIdx.x;
    __shared__ float shC[DD];
    if (t < DD) shC[t] = cand[b * DD + t];
    __syncthreads();
    unsigned short* wb = WbG + (size_t)b * (NP * DD);
#pragma unroll
    for (int u = 0; u < 12; ++u) {
        int e = t + u * 256;
        int n = e >> 6, k = e & 63;
        float val = 0.f;
        if (n < HH)
            val = W1[(DD + k) * HH + n] - W1[(2 * DD + k) * HH + n] +
                  shC[k] * W1[(3 * DD + k) * HH + n];
        wb[e] = f2bf(val);
    }
    if (t < NP) {
        float v = 0.f;
        if (t < HH) {
            v = b1[t];
            for (int k = 0; k < DD; ++k)
                v += shC[k] * (W1[k * HH + t] + W1[(2 * DD + k) * HH + t]);
        }
        baseG[b * NP + t] = v;
    }
}

template <bool WB>
__device__ __forceinline__ void prologue(int b, int half, int t,
                                         const float* __restrict__ hist,
                                         const float* __restrict__ cand,
                                         const float* __restrict__ W1,
                                         const float* __restrict__ b1,
                                         const unsigned short* __restrict__ WbG,
                                         const float* __restrict__ baseG,
                                         unsigned short* shH, unsigned short* shWbT,
                                         float* shC, float* shBase,
                                         float (*shBaseP)[NP]) {
    const float4* src =
        (const float4*)(hist + ((size_t)b * SS + (half ? 112 : 0)) * DD);
    float4 v[7];
    uint4 w0 = {}, w1 = {};
    float bse = 0.f;
    if (WB) {
        const uint4* wsrc = (const uint4*)(WbG + (size_t)b * (NP * DD));
        w0 = wsrc[t];
        if (t < 128) w1 = wsrc[256 + t];
        if (t < NP) bse = baseG[b * NP + t];
    } else {
        if (t < DD) shC[t] = cand[b * DD + t];
    }
    if (!half) {
#pragma unroll
        for (int u = 0; u < 7; ++u) v[u] = src[t + u * 256];
    } else {
#pragma unroll
        for (int u = 0; u < 5; ++u) v[u] = src[t + u * 256];
        if (t < 128) v[5] = src[t + 1280];
        *(unsigned*)&shH[(88 + (t >> 5)) * LDH + (t & 31) * 2] = 0;
    }
    if (!WB) __syncthreads();
#pragma unroll
    for (int u = 0; u < 7; ++u) {
        int i = t + u * 256;
        bool act = half ? (u < 5 || (u == 5 && t < 128)) : true;
        if (u < 6 || !half) {
            if (act) {
                int s = i >> 4, c = i & 15;
                uint2 o = {f2bf2(v[u].x, v[u].y), f2bf2(v[u].z, v[u].w)};
                *(uint2*)&shH[s * LDH + c * 4] = o;
            }
        }
    }
    if (WB) {
        *(uint4*)&shWbT[(t >> 3) * LDH + (t & 7) * 8] = w0;
        if (t < 128) *(uint4*)&shWbT[(32 + (t >> 3)) * LDH + (t & 7) * 8] = w1;
        if (t < NP) shBase[t] = bse;
        __syncthreads();
    } else {
        for (int e = t; e < NP * DD; e += 256) {
            int n = e >> 6, k = e & 63;
            float val = 0.f;
            if (n < HH)
                val = W1[(DD + k) * HH + n] - W1[(2 * DD + k) * HH + n] +
                      shC[k] * W1[(3 * DD + k) * HH + n];
            shWbT[n * LDH + k] = f2bf(val);
        }
        if (t < 4 * NP) {
            int g = t / NP, j = t - g * NP;
            float p = 0.f;
            if (j < HH) {
#pragma unroll 4
                for (int k = 16 * g; k < 16 * g + 16; ++k)
                    p += shC[k] * (W1[k * HH + j] + W1[(2 * DD + k) * HH + j]);
            }
            shBaseP[g][j] = p;
        }
        __syncthreads();
        if (t < NP) {
            float val = (t < HH) ? b1[t] : 0.f;
            shBase[t] = val + shBaseP[0][t] + shBaseP[1][t] + shBaseP[2][t] +
                        shBaseP[3][t];
        }
        __syncthreads();
    }
}

template <bool WB, bool RED>
__global__ __launch_bounds__(256, 6) void k_pass1(const float* __restrict__ hist,
                                                  const float* __restrict__ cand,
                                                  const float* __restrict__ W1,
                                                  const float* __restrict__ b1,
                                                  const unsigned short* __restrict__ WbG,
                                                  const float* __restrict__ baseG,
                                                  float* __restrict__ pstat,
                                                  float* __restrict__ gsum,
                                                  float* __restrict__ gsum2) {
    __shared__ unsigned short shH[112 * LDH];
    __shared__ unsigned short shWbT[NP * LDH];
    __shared__ float shC[WB ? 1 : DD], shBase[NP];
    __shared__ float shBaseP[WB ? 1 : 4][NP];
    __shared__ float shP1[4][NP], shP2[4][NP];
    int bx = blockIdx.x, b = bx >> 1, half = bx & 1;
    int t = threadIdx.x, wave = t >> 6, lane = t & 63;
    int col = lane & 15, q = lane >> 4;

    prologue<WB>(b, half, t, hist, cand, W1, b1, WbG, baseG, shH, shWbT, shC,
                 shBase, shBaseP);
    bf16x8 bfr[3][2];
    load_bfrags(shWbT, lane, bfr);
    float basev[3];
#pragma unroll
    for (int nt = 0; nt < 3; ++nt) basev[nt] = shBase[nt * 16 + col];

    const int NTl = half ? 6 : 7;
    float cs1[3] = {0.f, 0.f, 0.f}, cs2[3] = {0.f, 0.f, 0.f};
    for (int mt = wave; mt < NTl; mt += 4) {
        f32x4 d[3];
        gemm_tile(shH, bfr, mt, lane, d);
        if (half && mt == 5) {
            int grow0 = 192 + q * 4;
#pragma unroll
            for (int nt = 0; nt < 3; ++nt)
#pragma unroll
                for (int r = 0; r < 4; ++r)
                    if (grow0 + r < SS) {
                        float vv = d[nt][r] + basev[nt];
                        cs1[nt] += vv;
                        cs2[nt] += vv * vv;
                    }
        } else {
#pragma unroll
            for (int nt = 0; nt < 3; ++nt)
#pragma unroll
                for (int r = 0; r < 4; ++r) {
                    float vv = d[nt][r] + basev[nt];
                    cs1[nt] += vv;
                    cs2[nt] += vv * vv;
                }
        }
    }
#pragma unroll
    for (int nt = 0; nt < 3; ++nt) {
        cs1[nt] += __shfl_xor(cs1[nt], 16);
        cs1[nt] += __shfl_xor(cs1[nt], 32);
        cs2[nt] += __shfl_xor(cs2[nt], 16);
        cs2[nt] += __shfl_xor(cs2[nt], 32);
    }
    if (lane < 16) {
#pragma unroll
        for (int nt = 0; nt < 3; ++nt) {
            shP1[wave][nt * 16 + lane] = cs1[nt];
            shP2[wave][nt * 16 + lane] = cs2[nt];
        }
    }
    __syncthreads();
    if (RED) {
        if (t < HH)
            pstat[(size_t)bx * PSTRIDE + t] =
                shP1[0][t] + shP1[1][t] + shP1[2][t] + shP1[3][t];
        else if (t < 2 * HH) {
            int f = t - HH;
            pstat[(size_t)bx * PSTRIDE + t] =
                shP2[0][f] + shP2[1][f] + shP2[2][f] + shP2[3][f];
        }
    } else {
        if (t < HH) {
            atomicAdd(gsum + t, shP1[0][t] + shP1[1][t] + shP1[2][t] + shP1[3][t]);
            atomicAdd(gsum2 + t, shP2[0][t] + shP2[1][t] + shP2[2][t] + shP2[3][t]);
        }
    }
}

__global__ __launch_bounds__(256) void k_stats_red(const float* __restrict__ pstat,
                                                   const float* __restrict__ gamma,
                                                   const float* __restrict__ beta,
                                                   float* __restrict__ A,
                                                   float* __restrict__ Bc) {
    int f = blockIdx.x, t = threadIdx.x;
    if (f >= HH) {
        if (t == 0) { A[f] = 0.f; Bc[f] = 0.f; }
        return;
    }
    float s1 = 0.f, s2 = 0.f;
    for (int r = t; r < NPB; r += 256) {
        s1 += pstat[(size_t)r * PSTRIDE + f];
        s2 += pstat[(size_t)r * PSTRIDE + HH + f];
    }
#pragma unroll
    for (int off = 1; off < 64; off <<= 1) {
        s1 += __shfl_xor(s1, off);
        s2 += __shfl_xor(s2, off);
    }
    __shared__ float a1[4], a2[4];
    if ((t & 63) == 0) { a1[t >> 6] = s1; a2[t >> 6] = s2; }
    __syncthreads();
    if (t == 0) {
        s1 = a1[0] + a1[1] + a1[2] + a1[3];
        s2 = a2[0] + a2[1] + a2[2] + a2[3];
        float mu = s1 * (1.0f / NROWSF);
        float var = s2 * (1.0f / NROWSF) - mu * mu;
        float a = rsqrtf(var + 1e-5f) * gamma[f];
        A[f] = a;
        Bc[f] = beta[f] - mu * a;
    }
}

__global__ void k_stats(const float* __restrict__ gsum, const float* __restrict__ gsum2,
                        const float* __restrict__ gamma, const float* __restrict__ beta,
                        float* __restrict__ A, float* __restrict__ Bc) {
    int t = threadIdx.x;
    if (t < NP) {
        if (t < HH) {
            float mu = gsum[t] * (1.0f / NROWSF);
            float var = gsum2[t] * (1.0f / NROWSF) - mu * mu;
            float a = rsqrtf(var + 1e-5f) * gamma[t];
            A[t] = a;
            Bc[t] = beta[t] - mu * a;
        } else {
            A[t] = 0.f;
            Bc[t] = 0.f;
        }
    }
}

template <bool WB>
__global__ __launch_bounds__(256, 6) void k_pass2(const float* __restrict__ hist,
                                                  const float* __restrict__ cand,
                                                  const float* __restrict__ W1,
                                                  const float* __restrict__ b1,
                                                  const unsigned short* __restrict__ WbG,
                                                  const float* __restrict__ baseG,
                                                  const float* __restrict__ Acoef,
                                                  const float* __restrict__ Bcoef,
                                                  const float* __restrict__ alpha,
                                                  const float* __restrict__ W2,
                                                  const float* __restrict__ b2,
                                                  float* __restrict__ out) {
    __shared__ unsigned short shH[112 * LDH];
    __shared__ unsigned short shWbT[NP * LDH];
    __shared__ float shC[WB ? 1 : DD], shBase[NP];
    __shared__ float shBaseP[WB ? 1 : 4][NP];
    __shared__ float shW[112];
    __shared__ float shPool[4][DD];
    int bx = blockIdx.x, b = bx >> 1, half = bx & 1;
    int t = threadIdx.x, wave = t >> 6, lane = t & 63;
    int col = lane & 15, q = lane >> 4;

    prologue<WB>(b, half, t, hist, cand, W1, b1, WbG, baseG, shH, shWbT, shC,
                 shBase, shBaseP);
    bf16x8 bfr[3][2];
    load_bfrags(shWbT, lane, bfr);
    float baseAB[3], Ar[3], W2r[3];
#pragma unroll
    for (int nt = 0; nt < 3; ++nt) {
        int c = nt * 16 + col;
        Ar[nt] = Acoef[c];
        baseAB[nt] = fmaf(shBase[c], Ar[nt], Bcoef[c]);
        W2r[nt] = (c < HH) ? W2[c] : 0.f;
    }
    float alv = alpha[0], one_m_alv = 1.0f - alv, b2v = b2[0];

    const int NTl = half ? 6 : 7;
    for (int mt = wave; mt < NTl; mt += 4) {
        f32x4 d[3];
        gemm_tile(shH, bfr, mt, lane, d);
        float hp[3][4];
#pragma unroll
        for (int nt = 0; nt < 3; ++nt)
#pragma unroll
            for (int r = 0; r < 4; ++r)
                hp[nt][r] = fmaf(d[nt][r], Ar[nt], baseAB[nt]);
        float s1[4], s2[4], wsum[4];
#pragma unroll
        for (int r = 0; r < 4; ++r) {
            s1[r] = hp[0][r] + hp[1][r] + hp[2][r];
            s2[r] = hp[0][r] * hp[0][r] + hp[1][r] * hp[1][r] + hp[2][r] * hp[2][r];
            s1[r] += __shfl_xor(s1[r], 1);
            s1[r] += __shfl_xor(s1[r], 2);
            s1[r] += __shfl_xor(s1[r], 4);
            s1[r] += __shfl_xor(s1[r], 8);
            s2[r] += __shfl_xor(s2[r], 1);
            s2[r] += __shfl_xor(s2[r], 2);
            s2[r] += __shfl_xor(s2[r], 4);
            s2[r] += __shfl_xor(s2[r], 8);
        }
#pragma unroll
        for (int r = 0; r < 4; ++r) {
            float avg = s1[r] * (1.0f / (float)HH);
            float var = s2[r] * (1.0f / (float)HH) - avg * avg;
            float inv = rsqrtf(var + 1e-3f);
            float wv = 0.f;
#pragma unroll
            for (int nt = 0; nt < 3; ++nt) {
                float z = (hp[nt][r] - avg) * inv;
                float ps = 1.0f / (1.0f + __expf(-z));
                float f = fmaf(ps, one_m_alv, alv);
                wv = fmaf(hp[nt][r] * f, W2r[nt], wv);
            }
            wsum[r] = wv;
            wsum[r] += __shfl_xor(wsum[r], 1);
            wsum[r] += __shfl_xor(wsum[r], 2);
            wsum[r] += __shfl_xor(wsum[r], 4);
            wsum[r] += __shfl_xor(wsum[r], 8);
        }
        if (col == 0) {
            float4 o = {wsum[0] + b2v, wsum[1] + b2v, wsum[2] + b2v, wsum[3] + b2v};
            *(float4*)&shW[mt * 16 + q * 4] = o;
        }
    }
    __syncthreads();
    {
        const int nR = half ? 88 : 112;
        float p = 0.f;
        for (int s = wave; s < nR; s += 4)
            p = fmaf(shW[s], bf2f(shH[s * LDH + lane]), p);
        shPool[wave][lane] = p;
    }
    __syncthreads();
    if (t < DD)
        atomicAdd(out + b * DD + t,
                  shPool[0][t] + shPool[1][t] + shPool[2][t] + shPool[3][t]);
}

// ---------------------------------------------------------------------------
extern "C" void kernel_launch(void* const* d_in, const int* in_sizes, int n_in,
                              void* d_out, int out_size, void* d_ws, size_t ws_size,
                              hipStream_t stream) {
    const float* hist = (const float*)d_in[0];
    const float* cand = (const float*)d_in[1];
    const float* W1 = (const float*)d_in[2];
    const float* b1 = (const float*)d_in[3];
    const float* gamma = (const float*)d_in[4];
    const float* beta = (const float*)d_in[5];
    const float* alpha = (const float*)d_in[6];
    const float* W2 = (const float*)d_in[7];
    const float* b2 = (const float*)d_in[8];
    float* out = (float*)d_out;
    float* ws = (float*)d_ws;

    // fused tier layout: [ctr 4u][pstat GRID*80][A 48][Bc 48][hG 88 MB]
    const size_t ctrF = 4;
    const size_t pstatFsd = (size_t)GRID * PSTRIDE;       // 81920 floats
    const size_t hShorts = (size_t)NPB * 7 * HSLOT;       // 44,040,192 shorts
    const size_t fusedNeed = (ctrF + pstatFsd + 2 * NP) * 4 + hShorts * 2;

    const size_t pstatF = (size_t)NPB * PSTRIDE;
    const size_t baseF = (size_t)BB * NP;
    const size_t wbS = (size_t)BB * NP * DD;
    const size_t fullNeed = (pstatF + 2 * NP + baseF) * 4 + wbS * 2;
    const size_t midNeed = (pstatF + 2 * NP) * 4;

    if (ws_size >= fusedNeed) {
        unsigned* ctr = (unsigned*)ws;
        float* pstat = ws + ctrF;
        float* A = pstat + pstatFsd;
        float* Bc = A + NP;
        unsigned short* hG = (unsigned short*)(Bc + NP);
        hipMemsetAsync(ctr, 0, ctrF * sizeof(unsigned), stream);
        k_fused<<<GRID, 256, 0, stream>>>(hist, cand, W1, b1, gamma, beta, alpha,
                                          W2, b2, out, hG, pstat, A, Bc, ctr);
    } else if (ws_size >= fullNeed) {
        float* pstat = ws;
        float* A = pstat + pstatF;
        float* Bc = A + NP;
        float* baseG = Bc + NP;
        unsigned short* WbG = (unsigned short*)(baseG + baseF);
        hipMemsetAsync(out, 0, (size_t)out_size * sizeof(float), stream);
        k_wb<<<BB, 256, 0, stream>>>(cand, W1, b1, WbG, baseG);
        k_pass1<true, true><<<NPB, 256, 0, stream>>>(hist, cand, W1, b1, WbG, baseG,
                                                     pstat, nullptr, nullptr);
        k_stats_red<<<NP, 256, 0, stream>>>(pstat, gamma, beta, A, Bc);
        k_pass2<true><<<NPB, 256, 0, stream>>>(hist, cand, W1, b1, WbG, baseG, A, Bc,
                                               alpha, W2, b2, out);
    } else if (ws_size >= midNeed) {
        float* pstat = ws;
        float* A = pstat + pstatF;
        float* Bc = A + NP;
        hipMemsetAsync(out, 0, (size_t)out_size * sizeof(float), stream);
        k_pass1<false, true><<<NPB, 256, 0, stream>>>(hist, cand, W1, b1, nullptr,
                                                      nullptr, pstat, nullptr, nullptr);
        k_stats_red<<<NP, 256, 0, stream>>>(pstat, gamma, beta, A, Bc);
        k_pass2<false><<<NPB, 256, 0, stream>>>(hist, cand, W1, b1, nullptr, nullptr,
                                                A, Bc, alpha, W2, b2, out);
    } else {
        float* gsum = ws;
        float* gsum2 = ws + NP;
        float* A = ws + 2 * NP;
        float* Bc = ws + 3 * NP;
        hipMemsetAsync(ws, 0, 2 * NP * sizeof(float), stream);
        hipMemsetAsync(out, 0, (size_t)out_size * sizeof(float), stream);
        k_pass1<false, false><<<NPB, 256, 0, stream>>>(hist, cand, W1, b1, nullptr,
                                                       nullptr, nullptr, gsum, gsum2);
        k_stats<<<1, 64, 0, stream>>>(gsum, gsum2, gamma, beta, A, Bc);
        k_pass2<false><<<NPB, 256, 0, stream>>>(hist, cand, W1, b1, nullptr, nullptr,
                                                A, Bc, alpha, W2, b2, out);
    }
}